// Round 2
// baseline (520.586 us; speedup 1.0000x reference)
//
#include <hip/hip_runtime.h>
#include <hip/hip_bf16.h>

typedef __attribute__((ext_vector_type(8))) short short8;
typedef __attribute__((ext_vector_type(4))) short short4v;
typedef __attribute__((ext_vector_type(4))) float float4v;

static __device__ __forceinline__ float b2f(short s) {
    return __builtin_bit_cast(float, ((unsigned)(unsigned short)s) << 16);
}
// fp32 -> bf16 round-to-nearest-even (finite values only)
static __device__ __forceinline__ short f2b(float f) {
    unsigned x = __builtin_bit_cast(unsigned, f);
    unsigned r = (x + 0x7fffu + ((x >> 16) & 1u)) >> 16;
    return (short)r;
}

// ------------- convert fp32 -> bf16, n multiple of 1024 ------------------------
__global__ __launch_bounds__(256) void cvt_k(const float* __restrict__ in,
                                             short* __restrict__ out)
{
    const size_t i = ((size_t)blockIdx.x * 256 + threadIdx.x) * 4;
    const float4v v = *(const float4v*)&in[i];
    short4v s;
#pragma unroll
    for (int j = 0; j < 4; j++) s[j] = f2b(v[j]);
    *(short4v*)&out[i] = s;
}

// ------------- transpose+convert: out_bf16[C][R] = in_f32[R][C] ----------------
__global__ __launch_bounds__(256) void transpose_cvt_k(const float* __restrict__ in,
                                                       short* __restrict__ out,
                                                       int R, int C)
{
    __shared__ float tile[64][65];
    const int tx = threadIdx.x;
    const int r0 = blockIdx.y * 64, c0 = blockIdx.x * 64;
    const int lr = tx >> 4, lc = (tx & 15) * 4;
#pragma unroll
    for (int p = 0; p < 4; p++) {
        const float4v v = *(const float4v*)&in[(size_t)(r0 + lr + p * 16) * C + c0 + lc];
#pragma unroll
        for (int j = 0; j < 4; j++) tile[lr + p * 16][lc + j] = v[j];
    }
    __syncthreads();
    const int oc = tx >> 3, orr = (tx & 7) * 8;
#pragma unroll
    for (int p = 0; p < 2; p++) {
        const int c = oc + p * 32;
        short8 pk;
#pragma unroll
        for (int j = 0; j < 8; j++) pk[j] = f2b(tile[orr + j][c]);
        *(short8*)&out[(size_t)(c0 + c) * R + r0 + orr] = pk;
    }
}

// ---------------- GEMM: C[M,N] = X[M,K] @ Wt[N,K]^T, bf16 in, fp32 acc ---------
// MODE 0: out[((b*16+h)*1024+l)*64+d] = v*scale      (Q/K scatter to (B,H,L,dh))
// MODE 1: out[((b*16+h)*64+d)*1024+l] = v            (V^T scatter to (B,H,dh,L))
// MODE 2: out[m*N+n] = relu(v + bias[n])
// MODE 3: out[m*N+n] = v + bias[n] + res[m*N+n]
#define LDT 40
template<int MODE>
__global__ __launch_bounds__(256) void gemm_bt(const short* __restrict__ X,
                                               const short* __restrict__ Wt,
                                               short* __restrict__ out,
                                               const float* __restrict__ bias,
                                               const short* __restrict__ res,
                                               int M, int N, int K, float scale)
{
    __shared__ short As[128 * LDT];
    __shared__ short Bs[128 * LDT];
    const int tid = threadIdx.x;
    const int wave = tid >> 6, lane = tid & 63;
    const int quad = lane >> 4, l16 = lane & 15;
    const int m0 = blockIdx.y * 128, n0 = blockIdx.x * 128;
    const int wm = (wave >> 1) * 64, wn = (wave & 1) * 64;
    const int sr = tid >> 2, sc = (tid & 3) * 8;

    float4v acc[4][4] = {};

    for (int k0 = 0; k0 < K; k0 += 32) {
        *(short8*)&As[sr * LDT + sc]        = *(const short8*)&X[(size_t)(m0 + sr) * K + k0 + sc];
        *(short8*)&As[(sr + 64) * LDT + sc] = *(const short8*)&X[(size_t)(m0 + sr + 64) * K + k0 + sc];
        *(short8*)&Bs[sr * LDT + sc]        = *(const short8*)&Wt[(size_t)(n0 + sr) * K + k0 + sc];
        *(short8*)&Bs[(sr + 64) * LDT + sc] = *(const short8*)&Wt[(size_t)(n0 + sr + 64) * K + k0 + sc];
        __syncthreads();
        short8 af[4], bfr[4];
#pragma unroll
        for (int i = 0; i < 4; i++) af[i]  = *(const short8*)&As[(wm + i * 16 + l16) * LDT + quad * 8];
#pragma unroll
        for (int i = 0; i < 4; i++) bfr[i] = *(const short8*)&Bs[(wn + i * 16 + l16) * LDT + quad * 8];
#pragma unroll
        for (int mi = 0; mi < 4; mi++)
#pragma unroll
            for (int ni = 0; ni < 4; ni++)
                acc[mi][ni] = __builtin_amdgcn_mfma_f32_16x16x32_bf16(af[mi], bfr[ni], acc[mi][ni], 0, 0, 0);
        __syncthreads();
    }

#pragma unroll
    for (int mi = 0; mi < 4; mi++) {
#pragma unroll
        for (int ni = 0; ni < 4; ni++) {
            const int gn = n0 + wn + ni * 16 + l16;
            const float bv = (MODE >= 2) ? bias[gn] : 0.0f;
#pragma unroll
            for (int r = 0; r < 4; r++) {
                const int gm = m0 + wm + mi * 16 + quad * 4 + r;
                float v = acc[mi][ni][r];
                if (MODE == 0) {
                    v *= scale;
                    size_t a = ((size_t)((gm >> 10) * 16 + (gn >> 6)) << 16) + ((size_t)(gm & 1023) << 6) + (gn & 63);
                    out[a] = f2b(v);
                } else if (MODE == 1) {
                    size_t a = ((size_t)((gm >> 10) * 16 + (gn >> 6)) << 16) + ((size_t)(gn & 63) << 10) + (gm & 1023);
                    out[a] = f2b(v);
                } else if (MODE == 2) {
                    v += bv;
                    v = fmaxf(v, 0.0f);
                    out[(size_t)gm * N + gn] = f2b(v);
                } else {
                    v += bv + b2f(res[(size_t)gm * N + gn]);
                    out[(size_t)gm * N + gn] = f2b(v);
                }
            }
        }
    }
}

// ---------------- attention: flash-style, one wave = 16 q-rows -----------------
// Qb,Kb: (B,H,L,dh) bf16 (Q pre-scaled by 1/8). Vt: (B,H,dh,L). mask: (B,L) int.
// heads out: (B,L,H*dh) bf16.
__global__ __launch_bounds__(256) void attn_k(const short* __restrict__ Qb,
                                              const short* __restrict__ Kb,
                                              const short* __restrict__ Vt,
                                              const int* __restrict__ mask,
                                              short* __restrict__ heads)
{
    __shared__ short P[4][16 * 40];
    const int bh = blockIdx.x, qb = blockIdx.y;
    const int b = bh >> 4, h = bh & 15;
    const int tid = threadIdx.x, wave = tid >> 6, lane = tid & 63;
    const int quad = lane >> 4, l16 = lane & 15;
    const int qbase = qb * 64 + wave * 16;
    const short* Qp = Qb + ((size_t)bh << 16) + (size_t)qbase * 64;
    const short* Kp = Kb + ((size_t)bh << 16);
    const short* Vp = Vt + ((size_t)bh << 16);
    const int* mp = mask + (b << 10);

    const short8 aq0 = *(const short8*)&Qp[l16 * 64 + quad * 8];
    const short8 aq1 = *(const short8*)&Qp[l16 * 64 + 32 + quad * 8];

    float m_r[4] = {-1e30f, -1e30f, -1e30f, -1e30f};
    float l_r[4] = {0.f, 0.f, 0.f, 0.f};
    float4v o[4] = {};
    short* myP = &P[wave][0];

    for (int kc = 0; kc < 1024; kc += 32) {
        float4v s0 = {}, s1 = {};
        {
            const short8 k00 = *(const short8*)&Kp[(kc + l16) * 64 + quad * 8];
            const short8 k01 = *(const short8*)&Kp[(kc + l16) * 64 + 32 + quad * 8];
            s0 = __builtin_amdgcn_mfma_f32_16x16x32_bf16(aq0, k00, s0, 0, 0, 0);
            s0 = __builtin_amdgcn_mfma_f32_16x16x32_bf16(aq1, k01, s0, 0, 0, 0);
            const short8 k10 = *(const short8*)&Kp[(kc + 16 + l16) * 64 + quad * 8];
            const short8 k11 = *(const short8*)&Kp[(kc + 16 + l16) * 64 + 32 + quad * 8];
            s1 = __builtin_amdgcn_mfma_f32_16x16x32_bf16(aq0, k10, s1, 0, 0, 0);
            s1 = __builtin_amdgcn_mfma_f32_16x16x32_bf16(aq1, k11, s1, 0, 0, 0);
        }
        const bool ok0 = mp[kc + l16] != 0;
        const bool ok1 = mp[kc + 16 + l16] != 0;
        float mx[4], p0[4], p1[4];
#pragma unroll
        for (int r = 0; r < 4; r++) {
            const float a = ok0 ? s0[r] : -1e10f;
            const float c = ok1 ? s1[r] : -1e10f;
            p0[r] = a; p1[r] = c;
            mx[r] = fmaxf(a, c);
        }
#pragma unroll
        for (int off = 1; off < 16; off <<= 1)
#pragma unroll
            for (int r = 0; r < 4; r++) mx[r] = fmaxf(mx[r], __shfl_xor(mx[r], off));
        float alpha[4], rs[4];
#pragma unroll
        for (int r = 0; r < 4; r++) {
            const float mn = fmaxf(m_r[r], mx[r]);
            alpha[r] = __expf(m_r[r] - mn);
            m_r[r] = mn;
            p0[r] = __expf(p0[r] - mn);
            p1[r] = __expf(p1[r] - mn);
            rs[r] = p0[r] + p1[r];
        }
#pragma unroll
        for (int off = 1; off < 16; off <<= 1)
#pragma unroll
            for (int r = 0; r < 4; r++) rs[r] += __shfl_xor(rs[r], off);
#pragma unroll
        for (int r = 0; r < 4; r++) l_r[r] = l_r[r] * alpha[r] + rs[r];
#pragma unroll
        for (int dt = 0; dt < 4; dt++)
#pragma unroll
            for (int r = 0; r < 4; r++) o[dt][r] *= alpha[r];

        __syncthreads();  // protect previous iter's P reads before overwrite
#pragma unroll
        for (int r = 0; r < 4; r++) {
            myP[(quad * 4 + r) * 40 + l16]      = f2b(p0[r]);
            myP[(quad * 4 + r) * 40 + 16 + l16] = f2b(p1[r]);
        }
        __syncthreads();  // P visible before A-frag reads
        const short8 ap = *(const short8*)&myP[l16 * 40 + quad * 8];
#pragma unroll
        for (int dt = 0; dt < 4; dt++) {
            const short8 bv = *(const short8*)&Vp[(dt * 16 + l16) * 1024 + kc + quad * 8];
            o[dt] = __builtin_amdgcn_mfma_f32_16x16x32_bf16(ap, bv, o[dt], 0, 0, 0);
        }
    }

    float inv[4];
#pragma unroll
    for (int r = 0; r < 4; r++) inv[r] = 1.0f / fmaxf(l_r[r], 1e-20f);
#pragma unroll
    for (int dt = 0; dt < 4; dt++)
#pragma unroll
        for (int r = 0; r < 4; r++) {
            const int gq = qbase + quad * 4 + r;
            heads[((size_t)(b * 1024 + gq) << 10) + h * 64 + dt * 16 + l16] = f2b(o[dt][r] * inv[r]);
        }
}

// ---------------- LayerNorm over D=1024, one block per row ---------------------
// in bf16, g/be fp32; F32OUT: write fp32 (d_out) else bf16
template<bool F32OUT>
__global__ __launch_bounds__(256) void ln_k(const short* __restrict__ in,
                                            const float* __restrict__ g,
                                            const float* __restrict__ be,
                                            short* __restrict__ outb,
                                            float* __restrict__ outf)
{
    __shared__ float red[8];
    const int row = blockIdx.x, tid = threadIdx.x;
    const short* p = in + ((size_t)row << 10);
    float v[4];
#pragma unroll
    for (int i = 0; i < 4; i++) v[i] = b2f(p[tid + i * 256]);
    float s = v[0] + v[1] + v[2] + v[3];
#pragma unroll
    for (int off = 32; off; off >>= 1) s += __shfl_xor(s, off);
    if ((tid & 63) == 0) red[tid >> 6] = s;
    __syncthreads();
    const float mu = (red[0] + red[1] + red[2] + red[3]) * (1.0f / 1024.0f);
    float vs = 0.f;
#pragma unroll
    for (int i = 0; i < 4; i++) { const float d = v[i] - mu; vs += d * d; }
#pragma unroll
    for (int off = 32; off; off >>= 1) vs += __shfl_xor(vs, off);
    if ((tid & 63) == 0) red[4 + (tid >> 6)] = vs;
    __syncthreads();
    const float rstd = rsqrtf((red[4] + red[5] + red[6] + red[7]) * (1.0f / 1024.0f) + 1e-5f);
#pragma unroll
    for (int i = 0; i < 4; i++) {
        const int c = tid + i * 256;
        const float r = (v[i] - mu) * rstd * g[c] + be[c];
        if (F32OUT) outf[((size_t)row << 10) + c] = r;
        else        outb[((size_t)row << 10) + c] = f2b(r);
    }
}

extern "C" void kernel_launch(void* const* d_in, const int* in_sizes, int n_in,
                              void* d_out, int out_size, void* d_ws, size_t ws_size,
                              hipStream_t stream)
{
    const float* x   = (const float*)d_in[0];
    const int*   mk  = (const int*)d_in[1];
    const float* Wq  = (const float*)d_in[2];
    const float* Wk  = (const float*)d_in[3];
    const float* Wv  = (const float*)d_in[4];
    const float* Wp  = (const float*)d_in[5];
    const float* bp  = (const float*)d_in[6];
    const float* W1  = (const float*)d_in[7];
    const float* b1  = (const float*)d_in[8];
    const float* W2  = (const float*)d_in[9];
    const float* b2  = (const float*)d_in[10];
    const float* g1  = (const float*)d_in[11];
    const float* be1 = (const float*)d_in[12];
    const float* g2  = (const float*)d_in[13];
    const float* be2 = (const float*)d_in[14];
    float* out = (float*)d_out;

    char* ws = (char*)d_ws;
    const size_t MB = (size_t)1 << 20;
    short* xb   = (short*)(ws + 0 * MB);    // 8 MB   x as bf16 (also residual 1)
    short* WqT  = (short*)(ws + 8 * MB);    // 2 MB
    short* WkT  = (short*)(ws + 10 * MB);   // 2 MB
    short* WvT  = (short*)(ws + 12 * MB);   // 2 MB
    short* WpT  = (short*)(ws + 14 * MB);   // 2 MB
    short* W1T  = (short*)(ws + 16 * MB);   // 8 MB
    short* W2T  = (short*)(ws + 24 * MB);   // 8 MB
    short* Qb   = (short*)(ws + 32 * MB);   // 8 MB
    short* Kb   = (short*)(ws + 40 * MB);   // 8 MB
    short* Vt   = (short*)(ws + 48 * MB);   // 8 MB
    short* hd   = (short*)(ws + 56 * MB);   // 8 MB
    short* u    = (short*)(ws + 32 * MB);   // 32 MB  (reuses Qb..hd after proj)
    short* hpre = (short*)(ws + 64 * MB);   // 8 MB
    short* hbuf = (short*)(ws + 72 * MB);   // 8 MB   (total 80 MB)

    const dim3 blk(256);

    // 0) x fp32 -> bf16
    cvt_k<<<dim3(4096), blk, 0, stream>>>(x, xb);

    // 1) weight transposes+convert -> (N,K) row-major bf16
    transpose_cvt_k<<<dim3(16, 16), blk, 0, stream>>>(Wq, WqT, 1024, 1024);
    transpose_cvt_k<<<dim3(16, 16), blk, 0, stream>>>(Wk, WkT, 1024, 1024);
    transpose_cvt_k<<<dim3(16, 16), blk, 0, stream>>>(Wv, WvT, 1024, 1024);
    transpose_cvt_k<<<dim3(16, 16), blk, 0, stream>>>(Wp, WpT, 1024, 1024);
    transpose_cvt_k<<<dim3(64, 16), blk, 0, stream>>>(W1, W1T, 1024, 4096);
    transpose_cvt_k<<<dim3(16, 64), blk, 0, stream>>>(W2, W2T, 4096, 1024);

    // 2) QKV projections (Q pre-scaled by 1/sqrt(dh)=0.125)
    gemm_bt<0><<<dim3(8, 32), blk, 0, stream>>>(xb, WqT, Qb, nullptr, nullptr, 4096, 1024, 1024, 0.125f);
    gemm_bt<0><<<dim3(8, 32), blk, 0, stream>>>(xb, WkT, Kb, nullptr, nullptr, 4096, 1024, 1024, 1.0f);
    gemm_bt<1><<<dim3(8, 32), blk, 0, stream>>>(xb, WvT, Vt, nullptr, nullptr, 4096, 1024, 1024, 1.0f);

    // 3) attention -> heads (B,L,D)
    attn_k<<<dim3(64, 16), blk, 0, stream>>>(Qb, Kb, Vt, mk, hd);

    // 4) output projection + bias + residual(xb) -> hpre
    gemm_bt<3><<<dim3(8, 32), blk, 0, stream>>>(hd, WpT, hpre, bp, xb, 4096, 1024, 1024, 1.0f);

    // 5) LN1 -> hbuf (bf16)
    ln_k<false><<<dim3(4096), blk, 0, stream>>>(hpre, g1, be1, hbuf, nullptr);

    // 6) FF1 + bias + relu -> u
    gemm_bt<2><<<dim3(32, 32), blk, 0, stream>>>(hbuf, W1T, u, b1, nullptr, 4096, 4096, 1024, 1.0f);

    // 7) FF2 + bias + residual(hbuf) -> hpre
    gemm_bt<3><<<dim3(8, 32), blk, 0, stream>>>(u, W2T, hpre, b2, hbuf, 4096, 1024, 4096, 1.0f);

    // 8) LN2 -> out (fp32)
    ln_k<true><<<dim3(4096), blk, 0, stream>>>(hpre, g2, be2, nullptr, out);
}